// Round 9
// baseline (190.506 us; speedup 1.0000x reference)
//
#include <hip/hip_runtime.h>
#include <math.h>

// Problem constants (from reference): N=100000, S=64, Q=50, P=3
#define N_Q 50
#define N_P 3
#define N_S 64
#define ROW 150        // Q*P floats per pauli word
#define BLK_ROWS 256   // rows per block (4 per lane)
#define THREADS 512    // fast-path main: 8 waves; wave w handles s in [8w, 8w+8)
#define WAVES 8
#define SCHUNK 8
#define RPL 4          // rows per lane: row r -> nbase + 64*r + lane

#define TP_THREADS 256 // transpose+precompute kernel
#define TP_ROWS 128

// ws layout (bytes):
//   [0     .. 3128)    partials double[391]
//   [3200  .. +4)      done-counter int (zeroed by transpose_pre each launch)
//   [3264  .. +38400)  HP   float[Q][S][3]  normalized heads, q-major
//   [41664 .. +256)    hrv  float[S]        smoothed head ratios
//   [65536 .. +75*N*8) AT2  float2[75][N]   column-pair-transposed A (fast path)
#define WS_CNT_OFF 3200
#define WS_HP_OFF 3264
#define WS_HRV_OFF 41664
#define WS_AT_OFF 65536

__device__ __forceinline__ float softplus20(float x) {
    float z = x * 20.0f;
    return fmaxf(z, 0.0f) + log1pf(expf(-fabsf(z)));  // stable softplus
}

// Fused: (a) blocks 0..12 compute HP/hrv/cnt (exact r0-verified math);
// (b) every block transposes its 128-row A tile into AT2[j2][n].
// Reads coalesced; writes coalesced along n; LDS stride 151 (coprime 32).
__global__ __launch_bounds__(TP_THREADS) void transpose_pre_kernel(
    const float* __restrict__ A, float2* __restrict__ AT2,
    const float* __restrict__ heads_param, const float* __restrict__ hr_param,
    float* __restrict__ HP, float* __restrict__ hrv, int* __restrict__ cnt,
    int N) {
    const int tid = threadIdx.x;

    // ---- fused precompute (grid >> 13 blocks needed; same math as r0) ----
    if (blockIdx.x == 0) {
        if (tid == 0) *cnt = 0;  // ws is re-poisoned every launch
        if (tid < N_S) {
            float sp = softplus20(hr_param[tid]);
            float tot = sp;
            #pragma unroll
            for (int off = 32; off; off >>= 1) tot += __shfl_xor(tot, off);
            float hr = sp / fmaxf(tot, 1e-12f);
            hrv[tid] = (hr + 0.001f / (float)N_S) / 1.001f;
        }
    }
    // EXACT reference semantics: h_p = sp_p / max(sum, EPS); when the clamp
    // fires the row does NOT sum to 1, so all three components are stored.
    {
        int idx = blockIdx.x * TP_THREADS + tid;
        if (idx < N_S * N_Q) {
            int q = idx / N_S;
            int s = idx - q * N_S;
            const float* hp = heads_param + ((size_t)s * N_Q + q) * N_P;
            float sp0 = softplus20(hp[0]);
            float sp1 = softplus20(hp[1]);
            float sp2 = softplus20(hp[2]);
            float denom = fmaxf(sp0 + sp1 + sp2, 1e-12f);
            float* o = HP + ((size_t)q * N_S + s) * 3;
            o[0] = sp0 / denom;
            o[1] = sp1 / denom;
            o[2] = sp2 / denom;
        }
    }

    // ---- tile transpose: A[n][150] -> AT2[j2][n], 128 rows per block ----
    __shared__ float tile[TP_ROWS * 151];   // 77312 B
    const int nbase = blockIdx.x * TP_ROWS;
    const float2* __restrict__ Asrc = (const float2*)A;
    for (int g = tid; g < TP_ROWS * (ROW / 2); g += TP_THREADS) {
        int r = g / (ROW / 2);
        int j = g - r * (ROW / 2);
        int src = nbase + r; if (src >= N) src = N - 1;   // clamp (harmless)
        float2 v = Asrc[(size_t)src * (ROW / 2) + j];
        tile[r * 151 + 2 * j]     = v.x;
        tile[r * 151 + 2 * j + 1] = v.y;
    }
    __syncthreads();
    for (int g = tid; g < (ROW / 2) * TP_ROWS; g += TP_THREADS) {
        int j2 = g >> 7;          // wave-uniform (128 | 64)
        int nloc = g & 127;
        int n = nbase + nloc;
        if (n < N) {
            float2 v = make_float2(tile[nloc * 151 + 2 * j2],
                                   tile[nloc * 151 + 2 * j2 + 1]);
            AT2[(size_t)j2 * N + n] = v;
        }
    }
}

// One q, 8 s-values (2 groups of 4), applied to FOUR rows sharing the H
// reads. Hq is wave-uniform -> conflict-free LDS broadcast (proven path).
// Per-(s,q,row) math order identical to all verified rounds.
__device__ __forceinline__ void computeQ4(const float4* __restrict__ Hq,
                                          const float (&a)[RPL][3],
                                          float (&p)[RPL][SCHUNK]) {
    #pragma unroll
    for (int g = 0; g < SCHUNK / 4; ++g) {
        float4 b0 = Hq[3 * g], b1 = Hq[3 * g + 1], b2 = Hq[3 * g + 2];
        // layout per 4 s: [h00 h01 h02 h10][h11 h12 h20 h21][h22 h30 h31 h32]
        #pragma unroll
        for (int r = 0; r < RPL; ++r) {
            p[r][4*g+0] *= fmaf(b0.x, a[r][0], fmaf(b0.y, a[r][1], b0.z * a[r][2]));
            p[r][4*g+1] *= fmaf(b0.w, a[r][0], fmaf(b1.x, a[r][1], b1.y * a[r][2]));
            p[r][4*g+2] *= fmaf(b1.z, a[r][0], fmaf(b1.w, a[r][1], b2.x * a[r][2]));
            p[r][4*g+3] *= fmaf(b2.y, a[r][0], fmaf(b2.z, a[r][1], b2.w * a[r][2]));
        }
    }
}

// FAST path: 8 waves (2-4 per SIMD), coalesced AT2 reads, H-LDS broadcast.
__global__ __launch_bounds__(THREADS, 2) void main_kernel_t(
    const float2* __restrict__ AT2, const float* __restrict__ coeff,
    const float* __restrict__ HP, const float* __restrict__ hrv,
    double* __restrict__ partials, int* __restrict__ cnt,
    float* __restrict__ out, int N) {
    __shared__ float hHs[N_Q * N_S * 3];     // 38400 B, q-major
    __shared__ float hrvl[N_S];
    __shared__ float covs[WAVES][BLK_ROWS];  // 8192 B
    __shared__ double redd[4];
    __shared__ double redf[WAVES];
    __shared__ int isLast;

    const int tid = threadIdx.x;
    const int lane = tid & 63;
    const int wave = tid >> 6;
    const int nbase = blockIdx.x * BLK_ROWS;

    // --- stage H (+hrv) into LDS once per block, coalesced float4 ---
    for (int i = tid; i < (N_Q * N_S * 3) / 4; i += THREADS)
        ((float4*)hHs)[i] = ((const float4*)HP)[i];
    if (tid < N_S) hrvl[tid] = hrv[tid];
    __syncthreads();

    // lane owns rows nbase + 64r + lane, r=0..3; AT2 column n per row
    const float2* __restrict__ Qp[RPL];
    #pragma unroll
    for (int r = 0; r < RPL; ++r) {
        int n = nbase + 64 * r + lane;  if (n >= N) n = N - 1;
        Qp[r] = AT2 + n;
    }
    const size_t Ns = (size_t)N;

    float prod[RPL][SCHUNK];
    #pragma unroll
    for (int r = 0; r < RPL; ++r)
        #pragma unroll
        for (int i = 0; i < SCHUNK; ++i) prod[r][i] = 1.0f;

    // H base for this wave's s-chunk: q-row = 48 float4; wave offset 6*wave
    const float4* __restrict__ Hbase = (const float4*)hHs + 6 * wave;

    // window = 2 q = 3 float2 column-pairs; one-window prefetch per row
    float2 x[RPL][3];
    #pragma unroll
    for (int r = 0; r < RPL; ++r) {
        x[r][0] = Qp[r][0]; x[r][1] = Qp[r][Ns]; x[r][2] = Qp[r][2 * Ns];
    }

    size_t o = 0;
    #pragma unroll 5
    for (int w = 0; w < N_Q / 2; ++w) {
        const size_t on = (w < N_Q / 2 - 1) ? o + 3 * Ns : (size_t)0;  // clamped
        float2 nx[RPL][3];
        #pragma unroll
        for (int r = 0; r < RPL; ++r) {
            nx[r][0] = Qp[r][on]; nx[r][1] = Qp[r][on + Ns]; nx[r][2] = Qp[r][on + 2 * Ns];
        }
        const float4* Hq = Hbase + 96 * w;      // q = 2w -> row offset 2w*48
        float aq[RPL][3], cq[RPL][3];
        #pragma unroll
        for (int r = 0; r < RPL; ++r) {
            aq[r][0] = x[r][0].x; aq[r][1] = x[r][0].y; aq[r][2] = x[r][1].x;
            cq[r][0] = x[r][1].y; cq[r][1] = x[r][2].x; cq[r][2] = x[r][2].y;
        }
        computeQ4(Hq,      aq, prod);           // q = 2w
        computeQ4(Hq + 48, cq, prod);           // q = 2w+1
        #pragma unroll
        for (int r = 0; r < RPL; ++r) {
            x[r][0] = nx[r][0]; x[r][1] = nx[r][1]; x[r][2] = nx[r][2];
        }
        o = on;
    }

    // ratio-weighted partial per row (8-long fmaf chain, verified r4 order)
    const int s0 = wave * SCHUNK;
    #pragma unroll
    for (int r = 0; r < RPL; ++r) {
        float acc = 0.0f;
        #pragma unroll
        for (int i = 0; i < SCHUNK; ++i) acc = fmaf(hrvl[s0 + i], prod[r][i], acc);
        covs[wave][64 * r + lane] = acc;
    }
    __syncthreads();

    // waves 0..3 finalize rows [64w, 64w+64); sequential 8-wave cov sum
    // (same association as the verified r4 8-wave epilogue: absmax stayed 0)
    if (wave < 4) {
        const int row = 64 * wave + lane;
        const int n = nbase + row;
        float cov = 0.0f;
        #pragma unroll
        for (int wv = 0; wv < WAVES; ++wv) cov += covs[wv][row];
        float term = 0.0f;
        if (n < N) { float c = coeff[n]; term = (c * c) / cov; }
        double td = (double)term;
        #pragma unroll
        for (int off = 32; off; off >>= 1) td += __shfl_down(td, off);
        if (lane == 0) redd[wave] = td;
    }
    __syncthreads();

    if (tid == 0) {
        partials[blockIdx.x] = ((redd[0] + redd[1]) + redd[2]) + redd[3];
        __threadfence();                 // release partial
        int v = atomicAdd(cnt, 1);
        isLast = (v == (int)gridDim.x - 1);
    }
    __syncthreads();

    if (isLast) {                        // last-finishing block reduces all
        __threadfence();                 // acquire
        double s = 0.0;
        for (int i = tid; i < (int)gridDim.x; i += THREADS) s += partials[i];
        #pragma unroll
        for (int off = 32; off; off >>= 1) s += __shfl_down(s, off);
        if (lane == 0) redf[wave] = s;
        __syncthreads();
        if (tid == 0) {
            double t = 0.0;
            #pragma unroll
            for (int wv = 0; wv < WAVES; ++wv) t += redf[wv];
            out[0] = (float)t;
        }
    }
}

// FALLBACK path (workspace too small for AT2): round-7 kernel verbatim
// (4 waves, 256 threads, SCHUNK=16, scattered A loads).
__global__ __launch_bounds__(256, 2) void main_kernel_f(
    const float* __restrict__ A, const float* __restrict__ coeff,
    const float* __restrict__ HP, const float* __restrict__ hrv,
    double* __restrict__ partials, int* __restrict__ cnt,
    float* __restrict__ out, int N) {
    __shared__ float hHs[N_Q * N_S * 3];
    __shared__ float hrvl[N_S];
    __shared__ float covs[4][BLK_ROWS];
    __shared__ double redd[4];
    __shared__ double redf[4];
    __shared__ int isLast;

    const int tid = threadIdx.x;
    const int lane = tid & 63;
    const int wave = tid >> 6;
    const int nbase = blockIdx.x * BLK_ROWS;

    for (int i = tid; i < (N_Q * N_S * 3) / 4; i += 256)
        ((float4*)hHs)[i] = ((const float4*)HP)[i];
    if (tid < N_S) hrvl[tid] = hrv[tid];
    __syncthreads();

    const float2* __restrict__ pR[RPL];
    #pragma unroll
    for (int r = 0; r < RPL; ++r) {
        int n = nbase + 64 * r + lane;  if (n >= N) n = N - 1;
        pR[r] = (const float2*)A + (size_t)n * (ROW / 2);
    }

    float prod[RPL][16];
    #pragma unroll
    for (int r = 0; r < RPL; ++r)
        #pragma unroll
        for (int i = 0; i < 16; ++i) prod[r][i] = 1.0f;

    const float4* __restrict__ Hbase = (const float4*)hHs + 12 * wave;

    float2 x[RPL][3];
    #pragma unroll
    for (int r = 0; r < RPL; ++r) {
        x[r][0] = pR[r][0]; x[r][1] = pR[r][1]; x[r][2] = pR[r][2];
    }

    #pragma unroll 5
    for (int w = 0; w < N_Q / 2; ++w) {
        const int nb = (w < N_Q / 2 - 1) ? 3 * w + 3 : 0;
        float2 nx[RPL][3];
        #pragma unroll
        for (int r = 0; r < RPL; ++r) {
            nx[r][0] = pR[r][nb]; nx[r][1] = pR[r][nb + 1]; nx[r][2] = pR[r][nb + 2];
        }
        const float4* Hq = Hbase + 96 * w;
        #pragma unroll
        for (int g = 0; g < 4; ++g) {
            float4 b0 = Hq[3 * g], b1 = Hq[3 * g + 1], b2 = Hq[3 * g + 2];
            #pragma unroll
            for (int r = 0; r < RPL; ++r) {
                float a0 = x[r][0].x, a1 = x[r][0].y, a2 = x[r][1].x;
                prod[r][4*g+0] *= fmaf(b0.x, a0, fmaf(b0.y, a1, b0.z * a2));
                prod[r][4*g+1] *= fmaf(b0.w, a0, fmaf(b1.x, a1, b1.y * a2));
                prod[r][4*g+2] *= fmaf(b1.z, a0, fmaf(b1.w, a1, b2.x * a2));
                prod[r][4*g+3] *= fmaf(b2.y, a0, fmaf(b2.z, a1, b2.w * a2));
            }
        }
        const float4* Hq2 = Hq + 48;
        #pragma unroll
        for (int g = 0; g < 4; ++g) {
            float4 b0 = Hq2[3 * g], b1 = Hq2[3 * g + 1], b2 = Hq2[3 * g + 2];
            #pragma unroll
            for (int r = 0; r < RPL; ++r) {
                float a0 = x[r][1].y, a1 = x[r][2].x, a2 = x[r][2].y;
                prod[r][4*g+0] *= fmaf(b0.x, a0, fmaf(b0.y, a1, b0.z * a2));
                prod[r][4*g+1] *= fmaf(b0.w, a0, fmaf(b1.x, a1, b1.y * a2));
                prod[r][4*g+2] *= fmaf(b1.z, a0, fmaf(b1.w, a1, b2.x * a2));
                prod[r][4*g+3] *= fmaf(b2.y, a0, fmaf(b2.z, a1, b2.w * a2));
            }
        }
        #pragma unroll
        for (int r = 0; r < RPL; ++r) {
            x[r][0] = nx[r][0]; x[r][1] = nx[r][1]; x[r][2] = nx[r][2];
        }
    }

    const int s0 = wave * 16;
    #pragma unroll
    for (int r = 0; r < RPL; ++r) {
        float acc = 0.0f;
        #pragma unroll
        for (int i = 0; i < 16; ++i) acc = fmaf(hrvl[s0 + i], prod[r][i], acc);
        covs[wave][64 * r + lane] = acc;
    }
    __syncthreads();

    {
        const int row = 64 * wave + lane;
        const int n = nbase + row;
        float cov = covs[0][row] + covs[1][row] + covs[2][row] + covs[3][row];
        float term = 0.0f;
        if (n < N) { float c = coeff[n]; term = (c * c) / cov; }
        double td = (double)term;
        #pragma unroll
        for (int off = 32; off; off >>= 1) td += __shfl_down(td, off);
        if (lane == 0) redd[wave] = td;
    }
    __syncthreads();

    if (tid == 0) {
        partials[blockIdx.x] = ((redd[0] + redd[1]) + redd[2]) + redd[3];
        __threadfence();
        int v = atomicAdd(cnt, 1);
        isLast = (v == (int)gridDim.x - 1);
    }
    __syncthreads();

    if (isLast) {
        __threadfence();
        double s = 0.0;
        for (int i = tid; i < (int)gridDim.x; i += 256) s += partials[i];
        #pragma unroll
        for (int off = 32; off; off >>= 1) s += __shfl_down(s, off);
        if (lane == 0) redf[wave] = s;
        __syncthreads();
        if (tid == 0) {
            double t = 0.0;
            #pragma unroll
            for (int wv = 0; wv < 4; ++wv) t += redf[wv];
            out[0] = (float)t;
        }
    }
}

extern "C" void kernel_launch(void* const* d_in, const int* in_sizes, int n_in,
                              void* d_out, int out_size, void* d_ws, size_t ws_size,
                              hipStream_t stream) {
    const float* A           = (const float*)d_in[0];  // [N, Q, P]
    const float* coeff       = (const float*)d_in[1];  // [N]
    const float* heads_param = (const float*)d_in[2];  // [S, Q, P]
    const float* hr_param    = (const float*)d_in[3];  // [S]
    const int N = in_sizes[1];
    const int nblocks = (N + BLK_ROWS - 1) / BLK_ROWS;  // 391

    char* ws = (char*)d_ws;
    double* partials = (double*)ws;
    int*    cnt = (int*)(ws + WS_CNT_OFF);
    float*  HP  = (float*)(ws + WS_HP_OFF);
    float*  hrv = (float*)(ws + WS_HRV_OFF);
    float2* AT2 = (float2*)(ws + WS_AT_OFF);
    float*  out = (float*)d_out;

    const size_t at_bytes = (size_t)(ROW / 2) * (size_t)N * sizeof(float2);
    if (ws_size >= (size_t)WS_AT_OFF + at_bytes) {
        const int tblocks = (N + TP_ROWS - 1) / TP_ROWS;   // 782 (>= 13)
        transpose_pre_kernel<<<tblocks, TP_THREADS, 0, stream>>>(
            A, AT2, heads_param, hr_param, HP, hrv, cnt, N);
        main_kernel_t<<<nblocks, THREADS, 0, stream>>>(AT2, coeff, HP, hrv,
                                                       partials, cnt, out, N);
    } else {
        const int pre_blocks = (N_S * N_Q + 255) / 256;    // 13
        // standalone precompute path (no AT2 space): reuse fused kernel's
        // precompute via a tiny grid, then the scattered fallback main.
        transpose_pre_kernel<<<pre_blocks, TP_THREADS, 0, stream>>>(
            A, (float2*)(ws + WS_CNT_OFF + 64), heads_param, hr_param,
            HP, hrv, cnt, N);   // transpose part writes only n < 13*128 cols
        main_kernel_f<<<nblocks, 256, 0, stream>>>(A, coeff, HP, hrv,
                                                   partials, cnt, out, N);
    }
}

// Round 10
// 161.703 us; speedup vs baseline: 1.1781x; 1.1781x over previous
//
#include <hip/hip_runtime.h>
#include <math.h>

// Problem constants (from reference): N=100000, S=64, Q=50, P=3
#define N_Q 50
#define N_P 3
#define N_S 64
#define ROW 150        // Q*P floats per pauli word
#define TROWS 128      // rows per tile (2 per lane)
#define THREADS 512    // 8 waves; wave w handles s in [8w, 8w+8)
#define WAVES 8
#define SCHUNK 8
#define GRID 256       // exactly 1 block per CU: zero grid quantization
#define ASTRIDE 151    // LDS A-tile row stride: 151 coprime 32 -> b32 reads 2-way (free)
#define NF2 75         // float2 per A row
#define TF2 (TROWS * NF2)   // 9600 float2 per tile
#define NLD 19         // staging rounds: ceil(9600/512)

// ws layout (bytes):
//   [0     .. 2048)    partials double[256]
//   [3200  .. +4)      done-counter int (zeroed by precompute each launch)
//   [3264  .. +38400)  HP   float[Q][S][3]  normalized heads, q-major
//   [41664 .. +256)    hrv  float[S]        smoothed head ratios
#define WS_CNT_OFF 3200
#define WS_HP_OFF 3264
#define WS_HRV_OFF 41664

__device__ __forceinline__ float softplus20(float x) {
    float z = x * 20.0f;
    return fmaxf(z, 0.0f) + log1pf(expf(-fabsf(z)));  // stable softplus
}

__global__ void precompute_kernel(const float* __restrict__ heads_param,
                                  const float* __restrict__ hr_param,
                                  float* __restrict__ HP,
                                  float* __restrict__ hrv,
                                  int* __restrict__ cnt) {
    const int tid = threadIdx.x;
    if (blockIdx.x == 0) {
        if (tid == 0) *cnt = 0;  // ws is re-poisoned every launch
        if (tid < N_S) {
            float sp = softplus20(hr_param[tid]);
            float tot = sp;
            #pragma unroll
            for (int off = 32; off; off >>= 1) tot += __shfl_xor(tot, off);
            float hr = sp / fmaxf(tot, 1e-12f);
            hrv[tid] = (hr + 0.001f / (float)N_S) / 1.001f;
        }
    }
    // EXACT reference semantics: h_p = sp_p / max(sum, EPS); when the clamp
    // fires the row does NOT sum to 1, so all three components are stored.
    int idx = blockIdx.x * blockDim.x + tid;
    if (idx < N_S * N_Q) {
        int q = idx / N_S;
        int s = idx - q * N_S;
        const float* hp = heads_param + ((size_t)s * N_Q + q) * N_P;
        float sp0 = softplus20(hp[0]);
        float sp1 = softplus20(hp[1]);
        float sp2 = softplus20(hp[2]);
        float denom = fmaxf(sp0 + sp1 + sp2, 1e-12f);
        float* o = HP + ((size_t)q * N_S + s) * 3;
        o[0] = sp0 / denom;
        o[1] = sp1 / denom;
        o[2] = sp2 / denom;
    }
}

// One q, 8 s-values (2 groups of 4), applied to TWO rows sharing the H reads.
// Hq is wave-uniform LDS -> conflict-free broadcast (r0/r4-verified path).
// Per-(s,q,row) math order identical to all verified rounds.
__device__ __forceinline__ void computeQ2(const float4* __restrict__ Hq,
                                          float a0, float a1, float a2,
                                          float c0, float c1, float c2,
                                          float (&p)[SCHUNK], float (&p2)[SCHUNK]) {
    #pragma unroll
    for (int g = 0; g < SCHUNK / 4; ++g) {
        float4 b0 = Hq[3 * g], b1 = Hq[3 * g + 1], b2 = Hq[3 * g + 2];
        // layout per 4 s: [h00 h01 h02 h10][h11 h12 h20 h21][h22 h30 h31 h32]
        p [4*g+0] *= fmaf(b0.x, a0, fmaf(b0.y, a1, b0.z * a2));
        p2[4*g+0] *= fmaf(b0.x, c0, fmaf(b0.y, c1, b0.z * c2));
        p [4*g+1] *= fmaf(b0.w, a0, fmaf(b1.x, a1, b1.y * a2));
        p2[4*g+1] *= fmaf(b0.w, c0, fmaf(b1.x, c1, b1.y * c2));
        p [4*g+2] *= fmaf(b1.z, a0, fmaf(b1.w, a1, b2.x * a2));
        p2[4*g+2] *= fmaf(b1.z, c0, fmaf(b1.w, c1, b2.x * c2));
        p [4*g+3] *= fmaf(b2.y, a0, fmaf(b2.z, a1, b2.w * a2));
        p2[4*g+3] *= fmaf(b2.y, c0, fmaf(b2.z, c1, b2.w * c2));
    }
}

__global__ __launch_bounds__(THREADS, 2) void main_kernel(
    const float* __restrict__ A, const float* __restrict__ coeff,
    const float* __restrict__ HP, const float* __restrict__ hrv,
    double* __restrict__ partials, int* __restrict__ cnt,
    float* __restrict__ out, int N) {
    __shared__ float hHs[N_Q * N_S * 3];      // 38400 B, q-major (r0 path)
    __shared__ float Abuf[TROWS * ASTRIDE];   // 77312 B A-tile (r5 layout)
    __shared__ float hrvl[N_S];
    __shared__ float covs[WAVES][TROWS];      // 4096 B
    __shared__ double redd[2];
    __shared__ double redf[WAVES];
    __shared__ int isLast;

    const int tid = threadIdx.x;
    const int lane = tid & 63;
    const int wave = tid >> 6;

    // contiguous tile range for this block (782 tiles over 256 blocks)
    const int ntiles = (N + TROWS - 1) / TROWS;
    const int qn = ntiles / GRID, rn = ntiles % GRID;
    const int b = blockIdx.x;
    const int t0 = b * qn + (b < rn ? b : rn);
    const int tcnt = qn + (b < rn ? 1 : 0);

    // --- stage H (+hrv) into LDS once per block, coalesced float4 ---
    for (int i = tid; i < (N_Q * N_S * 3) / 4; i += THREADS)
        ((float4*)hHs)[i] = ((const float4*)HP)[i];
    if (tid < N_S) hrvl[tid] = hrv[tid];

    const float2* __restrict__ Ag = (const float2*)A;
    const size_t A2MAX = (size_t)N * NF2 - 1;   // clamp: dup of valid data, no OOB
    float2 st[NLD];

    // --- prologue: stage tile t0 (coalesced float2 global -> LDS) ---
    {
        const size_t base = (size_t)t0 * TF2;
        #pragma unroll
        for (int k = 0; k < NLD; ++k) {
            int idx = tid + (k << 9);
            if (idx < TF2) {
                size_t g = base + idx; if (g > A2MAX) g = A2MAX;
                st[k] = Ag[g];
            }
        }
        #pragma unroll
        for (int k = 0; k < NLD; ++k) {
            int idx = tid + (k << 9);
            if (idx < TF2) {
                int r = idx / NF2, c2 = idx - r * NF2;
                float* d = Abuf + r * ASTRIDE + 2 * c2;
                d[0] = st[k].x; d[1] = st[k].y;
            }
        }
    }
    __syncthreads();

    // lane owns LDS rows lane and lane+64 (r5-verified read pattern)
    const float* __restrict__ Ar0 = Abuf + lane * ASTRIDE;
    const float* __restrict__ Ar1 = Abuf + (lane + 64) * ASTRIDE;
    const float4* __restrict__ Hbase = (const float4*)hHs + 6 * wave;

    double bsum = 0.0;

    for (int ti = 0; ti < tcnt; ++ti) {
        const int t = t0 + ti;
        const bool have = (ti + 1 < tcnt);

        // T14 issue-early: next tile's global loads fly during this compute
        if (have) {
            const size_t base = (size_t)(t + 1) * TF2;
            #pragma unroll
            for (int k = 0; k < NLD; ++k) {
                int idx = tid + (k << 9);
                if (idx < TF2) {
                    size_t g = base + idx; if (g > A2MAX) g = A2MAX;
                    st[k] = Ag[g];
                }
            }
        }

        // --- compute: r5-verified inner loop (LDS A scalars + LDS H bcast) ---
        float prod0[SCHUNK], prod1[SCHUNK];
        #pragma unroll
        for (int i = 0; i < SCHUNK; ++i) { prod0[i] = 1.0f; prod1[i] = 1.0f; }

        #pragma unroll 5
        for (int w = 0; w < N_Q / 2; ++w) {   // window = 2 q = 6 floats/row
            const int o = 6 * w;
            float a0 = Ar0[o], a1 = Ar0[o+1], a2 = Ar0[o+2];
            float a3 = Ar0[o+3], a4 = Ar0[o+4], a5 = Ar0[o+5];
            float c0 = Ar1[o], c1 = Ar1[o+1], c2 = Ar1[o+2];
            float c3 = Ar1[o+3], c4 = Ar1[o+4], c5 = Ar1[o+5];
            const float4* Hq = Hbase + 96 * w;      // q = 2w
            computeQ2(Hq,      a0, a1, a2,  c0, c1, c2, prod0, prod1);
            computeQ2(Hq + 48, a3, a4, a5,  c3, c4, c5, prod0, prod1);
        }

        // ratio-weighted partials for both rows (r4-verified association)
        float acc0 = 0.0f, acc1 = 0.0f;
        const int s0 = wave * SCHUNK;
        #pragma unroll
        for (int i = 0; i < SCHUNK; ++i) {
            float wgt = hrvl[s0 + i];
            acc0 = fmaf(wgt, prod0[i], acc0);
            acc1 = fmaf(wgt, prod1[i], acc1);
        }
        covs[wave][lane] = acc0;
        covs[wave][64 + lane] = acc1;
        __syncthreads();   // all A-tile reads + covs writes complete

        // waves 0,1 finalize rows 0..63 / 64..127 (r4-verified 8-term sum)
        if (wave < 2) {
            const int row = wave * 64 + lane;
            const int n = t * TROWS + row;
            float cov = 0.0f;
            #pragma unroll
            for (int wv = 0; wv < WAVES; ++wv) cov += covs[wv][row];
            float term = 0.0f;
            if (n < N) { float c = coeff[n]; term = (c * c) / cov; }
            double td = (double)term;
            #pragma unroll
            for (int off = 32; off; off >>= 1) td += __shfl_down(td, off);
            if (lane == 0) redd[wave] = td;
        }

        // T14 write-late: staged regs -> LDS (safe: behind the read barrier)
        if (have) {
            #pragma unroll
            for (int k = 0; k < NLD; ++k) {
                int idx = tid + (k << 9);
                if (idx < TF2) {
                    int r = idx / NF2, c2 = idx - r * NF2;
                    float* d = Abuf + r * ASTRIDE + 2 * c2;
                    d[0] = st[k].x; d[1] = st[k].y;
                }
            }
        }
        __syncthreads();   // covs consumed + new tile visible

        if (tid == 0) bsum += redd[0] + redd[1];
    }

    if (tid == 0) {
        partials[b] = bsum;
        __threadfence();                 // release partial
        int v = atomicAdd(cnt, 1);
        isLast = (v == (int)gridDim.x - 1);
    }
    __syncthreads();

    if (isLast) {                        // last-finishing block reduces all
        __threadfence();                 // acquire
        double s = 0.0;
        for (int i = tid; i < (int)gridDim.x; i += THREADS) s += partials[i];
        #pragma unroll
        for (int off = 32; off; off >>= 1) s += __shfl_down(s, off);
        if (lane == 0) redf[wave] = s;
        __syncthreads();
        if (tid == 0) {
            double tsum = 0.0;
            #pragma unroll
            for (int wv = 0; wv < WAVES; ++wv) tsum += redf[wv];
            out[0] = (float)tsum;
        }
    }
}

extern "C" void kernel_launch(void* const* d_in, const int* in_sizes, int n_in,
                              void* d_out, int out_size, void* d_ws, size_t ws_size,
                              hipStream_t stream) {
    const float* A           = (const float*)d_in[0];  // [N, Q, P]
    const float* coeff       = (const float*)d_in[1];  // [N]
    const float* heads_param = (const float*)d_in[2];  // [S, Q, P]
    const float* hr_param    = (const float*)d_in[3];  // [S]
    const int N = in_sizes[1];

    char* ws = (char*)d_ws;
    double* partials = (double*)ws;
    int*   cnt = (int*)(ws + WS_CNT_OFF);
    float* HP  = (float*)(ws + WS_HP_OFF);
    float* hrv = (float*)(ws + WS_HRV_OFF);
    float* out = (float*)d_out;

    const int pre_blocks = (N_S * N_Q + 255) / 256;  // 13
    precompute_kernel<<<pre_blocks, 256, 0, stream>>>(heads_param, hr_param,
                                                      HP, hrv, cnt);
    main_kernel<<<GRID, THREADS, 0, stream>>>(A, coeff, HP, hrv, partials,
                                              cnt, out, N);
}